// Round 7
// baseline (244.471 us; speedup 1.0000x reference)
//
#include <hip/hip_runtime.h>
#include <math.h>

#define NPTS 300000
#define K 64
#define P 32
#define DETC 1e-16f
// one accumulator copy: [0,64) N_k | [64,128) S_k | [128,2176) M[d][k]
#define WS_FLOATS (K + K + K * P)
// striped copies to avoid same-line atomic serialization across 8 XCDs
#define NCOPIES 32

#define NTHREADS 256
#define WPB (NTHREADS / 64)                    // 4 waves / block
#define TILE 64                                // points per wave
#define NTILES ((NPTS + TILE - 1) / TILE)      // 4688 (last tile = 32 pts, exact)
#define NBLOCKS ((NTILES + WPB - 1) / WPB)     // 1172

typedef __attribute__((ext_vector_type(8)))  short    bf16x8;
typedef __attribute__((ext_vector_type(4)))  float    f32x4;
typedef __attribute__((ext_vector_type(16))) float    f32x16;
typedef __attribute__((ext_vector_type(4)))  unsigned u32x4;

#define MF16(a, b, c) __builtin_amdgcn_mfma_f32_16x16x32_bf16(a, b, c, 0, 0, 0)
#define MF32(a, b, c) __builtin_amdgcn_mfma_f32_32x32x16_bf16(a, b, c, 0, 0, 0)

// ---- DPP butterfly: after 4 steps each lane holds the sum over its 16-lane row
#define DPP_ADD(v, ctrl)                                                     \
    v += __int_as_float(__builtin_amdgcn_update_dpp(                         \
        0, __float_as_int(v), (ctrl), 0xF, 0xF, true))
#define DPP16(v) do { DPP_ADD(v, 0xB1); DPP_ADD(v, 0x4E);                    \
                      DPP_ADD(v, 0x128); DPP_ADD(v, 0x124); } while (0)

// pack 2 f32 -> 2 bf16 (RNE) in one dword (a = low half, b = high half)
__device__ __forceinline__ unsigned pkbf(float a, float b) {
    unsigned ua = __float_as_uint(a), ub = __float_as_uint(b);
    ua = (ua + 0x7fffu + ((ua >> 16) & 1u)) >> 16;
    ub = (ub + 0x7fffu + ((ub >> 16) & 1u)) & 0xffff0000u;
    return ua | ub;
}
// hi/lo bf16 split of the pair (xa,xb): dh = hi parts, dl = residual parts
#define PKHL(xa, xb, dh, dl) do {                                            \
    dh = pkbf((xa), (xb));                                                   \
    dl = pkbf((xa) - __uint_as_float(dh << 16),                              \
              (xb) - __uint_as_float(dh & 0xffff0000u)); } while (0)

__device__ __forceinline__ bf16x8 mkfrag(unsigned a, unsigned b, unsigned c, unsigned d) {
    u32x4 t = {a, b, c, d};
    return __builtin_bit_cast(bf16x8, t);
}

__global__ __launch_bounds__(NTHREADS, 2) void em_pass(
    const float* __restrict__ mu_phi,
    const float* __restrict__ log_cov_phi,
    const float* __restrict__ pi_k,
    const float* __restrict__ mu_k,
    const float* __restrict__ log_cov_k,
    float* __restrict__ gamma_out,
    float* __restrict__ out_tail,   // pi_new | mu_new | log_cov_new
    float* __restrict__ ws)
{
    const int lane = threadIdx.x & 63;
    const int wave = threadIdx.x >> 6;
    const int gw = __builtin_amdgcn_readfirstlane(blockIdx.x * WPB + wave); // tile id

    const int l15 = lane & 15;        // S-tile: cluster col (within 16)
    const int g4  = lane >> 4;        // S-tile: point-row group (rows 4*g4..+3)
    const int l31 = lane & 31;        // M-tile: d-row
    const int h   = lane >> 5;        // M-tile: k(p)-slice half
    const int b4  = g4 & 1;           // which half of 8 rows this lane owns

    // ================= prologue: per-cluster constants + Mk2 B-fragments ====
    // S-GEMM convention: A(phi): row=l15, k(d)=8*g4+j ; B(mk2): col=l15, k(d)=8*g4+j
    float nh0, nh1, nh2, nh3;         // -0.5*icov  per kt (cluster col l15+16kt)
    float Ak0, Ak1, Ak2, Ak3;         // Ak         per kt
    bf16x8 Bh0, Bh1, Bh2, Bh3, Bl0, Bl1, Bl2, Bl3;
#define MKB(kt, BH, BL, NHI, AKV) do {                                       \
        const int ck = l15 + 16 * (kt);                                      \
        const float4 m0 = *(const float4*)(mu_k + ck * P + 8 * g4);          \
        const float4 m1 = *(const float4*)(mu_k + ck * P + 8 * g4 + 4);      \
        float n2p = 0.f;                                                     \
        n2p = fmaf(m0.x, m0.x, n2p); n2p = fmaf(m0.y, m0.y, n2p);            \
        n2p = fmaf(m0.z, m0.z, n2p); n2p = fmaf(m0.w, m0.w, n2p);            \
        n2p = fmaf(m1.x, m1.x, n2p); n2p = fmaf(m1.y, m1.y, n2p);            \
        n2p = fmaf(m1.z, m1.z, n2p); n2p = fmaf(m1.w, m1.w, n2p);            \
        n2p += __shfl_xor(n2p, 16);  n2p += __shfl_xor(n2p, 32);             \
        const float lk = log_cov_k[ck];                                      \
        const float ic = __expf(-lk);                                        \
        NHI = -0.5f * ic;                                                    \
        AKV = 0.5f * (32.f * lk - 32.f + ic * n2p) - __logf(pi_k[ck]);       \
        unsigned q0, q1, q2, q3, r0, r1, r2, r3;                             \
        PKHL(ic * m0.x, ic * m0.y, q0, r0);                                  \
        PKHL(ic * m0.z, ic * m0.w, q1, r1);                                  \
        PKHL(ic * m1.x, ic * m1.y, q2, r2);                                  \
        PKHL(ic * m1.z, ic * m1.w, q3, r3);                                  \
        BH = mkfrag(q0, q1, q2, q3); BL = mkfrag(r0, r1, r2, r3); } while (0)
    MKB(0, Bh0, Bl0, nh0, Ak0);
    MKB(1, Bh1, Bl1, nh1, Ak1);
    MKB(2, Bh2, Bl2, nh2, Ak2);
    MKB(3, Bh3, Bl3, nh3, Ak3);
#undef MKB

    float accN0 = 0.f, accN1 = 0.f, accN2 = 0.f, accN3 = 0.f;
    float accS0 = 0.f, accS1 = 0.f, accS2 = 0.f, accS3 = 0.f;
    f32x16 accM0 = {};                // M[d][k], cols l31+0
    f32x16 accM1 = {};                // M[d][k], cols l31+32

    const int start = gw * TILE;
    const int cnt   = (NPTS - start < TILE) ? (NPTS - start) : TILE;
    const int nPt   = cnt >> 4;       // 4 (full tile) or 2 (exact 32-pt tail)

    for (int pt = 0; pt < nPt; ++pt) {
        const int rbase = start + pt * 16;

        // ---- A(phi) load: lane = row l15, d-slice 8*g4..+7 (coalesced) ----
        const float* prow = mu_phi + (size_t)(rbase + l15) * P + 8 * g4;
        const float4 p0 = *(const float4*)(prow);
        const float4 p1 = *(const float4*)(prow + 4);
        // phi^T for M-GEMM: lane = d-col l31, p = rbase + 8h + j (L1-warm rows)
        const float* pcol = mu_phi + (size_t)(rbase + 8 * h) * P + l31;
        const float t0 = pcol[0 * P], t1 = pcol[1 * P], t2 = pcol[2 * P], t3 = pcol[3 * P];
        const float t4 = pcol[4 * P], t5 = pcol[5 * P], t6 = pcol[6 * P], t7 = pcol[7 * P];

        // ---- u, bl for row l15 (full ||phi||^2 via 2 xor-shuffles) ----
        float n2 = 0.f;
        n2 = fmaf(p0.x, p0.x, n2); n2 = fmaf(p0.y, p0.y, n2);
        n2 = fmaf(p0.z, p0.z, n2); n2 = fmaf(p0.w, p0.w, n2);
        n2 = fmaf(p1.x, p1.x, n2); n2 = fmaf(p1.y, p1.y, n2);
        n2 = fmaf(p1.z, p1.z, n2); n2 = fmaf(p1.w, p1.w, n2);
        n2 += __shfl_xor(n2, 16); n2 += __shfl_xor(n2, 32);
        const float lcpv = log_cov_phi[rbase + l15];
        const float u_l  = fmaf(32.f, __expf(lcpv), n2);
        const float bl_l = 16.f * lcpv;

        // ---- A hi/lo split ----
        unsigned a0, a1, a2, a3, e0, e1, e2, e3;
        PKHL(p0.x, p0.y, a0, e0); PKHL(p0.z, p0.w, a1, e1);
        PKHL(p1.x, p1.y, a2, e2); PKHL(p1.z, p1.w, a3, e3);
        const bf16x8 Ah = mkfrag(a0, a1, a2, a3), Al = mkfrag(e0, e1, e2, e3);

        // ---- S = icov*dot, 3-term split, 4 cluster-tiles ----
        f32x4 s0 = {0.f, 0.f, 0.f, 0.f}, s1 = {0.f, 0.f, 0.f, 0.f};
        f32x4 s2 = {0.f, 0.f, 0.f, 0.f}, s3 = {0.f, 0.f, 0.f, 0.f};
        s0 = MF16(Ah, Bh0, s0); s0 = MF16(Ah, Bl0, s0); s0 = MF16(Al, Bh0, s0);
        s1 = MF16(Ah, Bh1, s1); s1 = MF16(Ah, Bl1, s1); s1 = MF16(Al, Bh1, s1);
        s2 = MF16(Ah, Bh2, s2); s2 = MF16(Ah, Bl2, s2); s2 = MF16(Al, Bh2, s2);
        s3 = MF16(Ah, Bh3, s3); s3 = MF16(Ah, Bl3, s3); s3 = MF16(Al, Bh3, s3);

        // ---- u, bl redistributed to this lane's 4 point-rows (4*g4+reg) ----
        const int sl = 4 * g4;
        const float u0 = __shfl(u_l, sl),     u1 = __shfl(u_l, sl + 1);
        const float u2 = __shfl(u_l, sl + 2), u3 = __shfl(u_l, sl + 3);
        const float b0 = __shfl(bl_l, sl),     b1 = __shfl(bl_l, sl + 1);
        const float b2 = __shfl(bl_l, sl + 2), b3 = __shfl(bl_l, sl + 3);

        // ---- w = exp(S + nhicov*u + bl - Ak)  (D layout: row=4*g4+reg, col=l15+16kt)
        const float w00 = __expf(s0[0] + fmaf(nh0, u0, b0 - Ak0));
        const float w01 = __expf(s0[1] + fmaf(nh0, u1, b1 - Ak0));
        const float w02 = __expf(s0[2] + fmaf(nh0, u2, b2 - Ak0));
        const float w03 = __expf(s0[3] + fmaf(nh0, u3, b3 - Ak0));
        const float w10 = __expf(s1[0] + fmaf(nh1, u0, b0 - Ak1));
        const float w11 = __expf(s1[1] + fmaf(nh1, u1, b1 - Ak1));
        const float w12 = __expf(s1[2] + fmaf(nh1, u2, b2 - Ak1));
        const float w13 = __expf(s1[3] + fmaf(nh1, u3, b3 - Ak1));
        const float w20 = __expf(s2[0] + fmaf(nh2, u0, b0 - Ak2));
        const float w21 = __expf(s2[1] + fmaf(nh2, u1, b1 - Ak2));
        const float w22 = __expf(s2[2] + fmaf(nh2, u2, b2 - Ak2));
        const float w23 = __expf(s2[3] + fmaf(nh2, u3, b3 - Ak2));
        const float w30 = __expf(s3[0] + fmaf(nh3, u0, b0 - Ak3));
        const float w31 = __expf(s3[1] + fmaf(nh3, u1, b1 - Ak3));
        const float w32 = __expf(s3[2] + fmaf(nh3, u2, b2 - Ak3));
        const float w33 = __expf(s3[3] + fmaf(nh3, u3, b3 - Ak3));

        // ---- softmax denominator: 3 lane-local adds + 16-lane DPP butterfly ----
        float r0 = (w00 + w10) + (w20 + w30);
        float r1 = (w01 + w11) + (w21 + w31);
        float r2 = (w02 + w12) + (w22 + w32);
        float r3 = (w03 + w13) + (w23 + w33);
        DPP16(r0); DPP16(r1); DPP16(r2); DPP16(r3);
        const float q0 = __builtin_amdgcn_rcpf(r0);
        const float q1 = __builtin_amdgcn_rcpf(r1);
        const float q2 = __builtin_amdgcn_rcpf(r2);
        const float q3 = __builtin_amdgcn_rcpf(r3);

        const float g00 = fmaf(w00, q0, DETC), g01 = fmaf(w01, q1, DETC);
        const float g02 = fmaf(w02, q2, DETC), g03 = fmaf(w03, q3, DETC);
        const float g10 = fmaf(w10, q0, DETC), g11 = fmaf(w11, q1, DETC);
        const float g12 = fmaf(w12, q2, DETC), g13 = fmaf(w13, q3, DETC);
        const float g20 = fmaf(w20, q0, DETC), g21 = fmaf(w21, q1, DETC);
        const float g22 = fmaf(w22, q2, DETC), g23 = fmaf(w23, q3, DETC);
        const float g30 = fmaf(w30, q0, DETC), g31 = fmaf(w31, q1, DETC);
        const float g32 = fmaf(w32, q2, DETC), g33 = fmaf(w33, q3, DETC);

        // ---- gamma store (row = rbase+4*g4+reg, col = l15+16kt) ----
        float* gp = gamma_out + (size_t)(rbase + sl) * K + l15;
        __builtin_nontemporal_store(g00, gp + 0 * K +  0);
        __builtin_nontemporal_store(g10, gp + 0 * K + 16);
        __builtin_nontemporal_store(g20, gp + 0 * K + 32);
        __builtin_nontemporal_store(g30, gp + 0 * K + 48);
        __builtin_nontemporal_store(g01, gp + 1 * K +  0);
        __builtin_nontemporal_store(g11, gp + 1 * K + 16);
        __builtin_nontemporal_store(g21, gp + 1 * K + 32);
        __builtin_nontemporal_store(g31, gp + 1 * K + 48);
        __builtin_nontemporal_store(g02, gp + 2 * K +  0);
        __builtin_nontemporal_store(g12, gp + 2 * K + 16);
        __builtin_nontemporal_store(g22, gp + 2 * K + 32);
        __builtin_nontemporal_store(g32, gp + 2 * K + 48);
        __builtin_nontemporal_store(g03, gp + 3 * K +  0);
        __builtin_nontemporal_store(g13, gp + 3 * K + 16);
        __builtin_nontemporal_store(g23, gp + 3 * K + 32);
        __builtin_nontemporal_store(g33, gp + 3 * K + 48);

        // ---- N_k, S_k partials (lane-local; combined via LDS atomics later) ----
        accN0 += (g00 + g01) + (g02 + g03);
        accN1 += (g10 + g11) + (g12 + g13);
        accN2 += (g20 + g21) + (g22 + g23);
        accN3 += (g30 + g31) + (g32 + g33);
        accS0 = fmaf(g00, u0, accS0); accS0 = fmaf(g01, u1, accS0);
        accS0 = fmaf(g02, u2, accS0); accS0 = fmaf(g03, u3, accS0);
        accS1 = fmaf(g10, u0, accS1); accS1 = fmaf(g11, u1, accS1);
        accS1 = fmaf(g12, u2, accS1); accS1 = fmaf(g13, u3, accS1);
        accS2 = fmaf(g20, u0, accS2); accS2 = fmaf(g21, u1, accS2);
        accS2 = fmaf(g22, u2, accS2); accS2 = fmaf(g23, u3, accS2);
        accS3 = fmaf(g30, u0, accS3); accS3 = fmaf(g31, u1, accS3);
        accS3 = fmaf(g32, u2, accS3); accS3 = fmaf(g33, u3, accS3);

        // ---- M-GEMM: accM[d][k] += phi^T * G  (K-step = this point-tile) ----
        // A(phi^T): row=l31(d), k(p)=8h+j ; B(G): col=l31(k), k(p)=8h+j.
        unsigned f0, f1, f2, f3, x0, x1, x2, x3;
        PKHL(t0, t1, f0, x0); PKHL(t2, t3, f1, x1);
        PKHL(t4, t5, f2, x2); PKHL(t6, t7, f3, x3);
        const bf16x8 Tp = mkfrag(f0, f1, f2, f3), Tl = mkfrag(x0, x1, x2, x3);

        // B-frag: own rows (4*g4..+3) at kt_own = b4+2ct; partner (lane^16)
        // supplies the other 4 rows; we pack+send kt_send = (1-b4)+2ct for it.
        {   // ct = 0  (cluster cols l31 + 0)
            const float o0 = b4 ? g10 : g00, o1 = b4 ? g11 : g01;
            const float o2 = b4 ? g12 : g02, o3 = b4 ? g13 : g03;
            const float z0 = b4 ? g00 : g10, z1 = b4 ? g01 : g11;
            const float z2 = b4 ? g02 : g12, z3 = b4 ? g03 : g13;
            unsigned oh0, ol0, oh1, ol1, zh0, zl0, zh1, zl1;
            PKHL(o0, o1, oh0, ol0); PKHL(o2, o3, oh1, ol1);
            PKHL(z0, z1, zh0, zl0); PKHL(z2, z3, zh1, zl1);
            const unsigned rh0 = __shfl_xor(zh0, 16), rh1 = __shfl_xor(zh1, 16);
            const unsigned rl0 = __shfl_xor(zl0, 16), rl1 = __shfl_xor(zl1, 16);
            const bf16x8 Bgh = mkfrag(b4 ? rh0 : oh0, b4 ? rh1 : oh1,
                                      b4 ? oh0 : rh0, b4 ? oh1 : rh1);
            const bf16x8 Bgl = mkfrag(b4 ? rl0 : ol0, b4 ? rl1 : ol1,
                                      b4 ? ol0 : rl0, b4 ? ol1 : rl1);
            accM0 = MF32(Tp, Bgh, accM0);
            accM0 = MF32(Tp, Bgl, accM0);
            accM0 = MF32(Tl, Bgh, accM0);
        }
        {   // ct = 1  (cluster cols l31 + 32)
            const float o0 = b4 ? g30 : g20, o1 = b4 ? g31 : g21;
            const float o2 = b4 ? g32 : g22, o3 = b4 ? g33 : g23;
            const float z0 = b4 ? g20 : g30, z1 = b4 ? g21 : g31;
            const float z2 = b4 ? g22 : g32, z3 = b4 ? g23 : g33;
            unsigned oh0, ol0, oh1, ol1, zh0, zl0, zh1, zl1;
            PKHL(o0, o1, oh0, ol0); PKHL(o2, o3, oh1, ol1);
            PKHL(z0, z1, zh0, zl0); PKHL(z2, z3, zh1, zl1);
            const unsigned rh0 = __shfl_xor(zh0, 16), rh1 = __shfl_xor(zh1, 16);
            const unsigned rl0 = __shfl_xor(zl0, 16), rl1 = __shfl_xor(zl1, 16);
            const bf16x8 Bgh = mkfrag(b4 ? rh0 : oh0, b4 ? rh1 : oh1,
                                      b4 ? oh0 : rh0, b4 ? oh1 : rh1);
            const bf16x8 Bgl = mkfrag(b4 ? rl0 : ol0, b4 ? rl1 : ol1,
                                      b4 ? ol0 : rl0, b4 ? ol1 : rl1);
            accM1 = MF32(Tp, Bgh, accM1);
            accM1 = MF32(Tp, Bgl, accM1);
            accM1 = MF32(Tl, Bgh, accM1);
        }
    }

    // ================= block combine in LDS, then striped global atomics ====
    __shared__ float red[WS_FLOATS];   // [0,K) N | [K,2K) S | [2K,..) M[d][k]
    for (int idx = threadIdx.x; idx < WS_FLOATS; idx += NTHREADS) red[idx] = 0.f;
    __syncthreads();

    atomicAdd(&red[l15 +  0], accN0); atomicAdd(&red[l15 + 16], accN1);
    atomicAdd(&red[l15 + 32], accN2); atomicAdd(&red[l15 + 48], accN3);
    atomicAdd(&red[K + l15 +  0], accS0); atomicAdd(&red[K + l15 + 16], accS1);
    atomicAdd(&red[K + l15 + 32], accS2); atomicAdd(&red[K + l15 + 48], accS3);
    // accM D-layout (32x32): col = l31 (+32*ct), row(d) = (r&3)+8*(r>>2)+4*h
#pragma unroll
    for (int r = 0; r < 16; ++r) {
        const int d = (r & 3) + 8 * (r >> 2) + 4 * h;
        atomicAdd(&red[2 * K + d * K + l31],      accM0[r]);
        atomicAdd(&red[2 * K + d * K + l31 + 32], accM1[r]);
    }
    __syncthreads();

    // striped cross-block combine: contention per address = NBLOCKS/NCOPIES
    float* wsc = ws + (size_t)(blockIdx.x & (NCOPIES - 1)) * WS_FLOATS;
    for (int idx = threadIdx.x; idx < WS_FLOATS; idx += NTHREADS)
        atomicAdd(&wsc[idx], red[idx]);
    __syncthreads();   // all this block's global atomics drained

    // ---- decoupled finalize: last block reduces the copies + small outputs ----
    __shared__ int lastf;
    if (threadIdx.x == 0) {
        __threadfence();
        const int c = atomicAdd((int*)(ws + (size_t)NCOPIES * WS_FLOATS), 1);
        lastf = (c == NBLOCKS - 1);
    }
    __syncthreads();
    if (lastf) {
        __threadfence();
        for (int idx = threadIdx.x; idx < WS_FLOATS; idx += NTHREADS) {
            float s = 0.f;
#pragma unroll 4
            for (int c = 0; c < NCOPIES; ++c)
                s += __hip_atomic_load(&ws[(size_t)c * WS_FLOATS + idx],
                                       __ATOMIC_RELAXED, __HIP_MEMORY_SCOPE_AGENT);
            red[idx] = s;
        }
        __syncthreads();

        const int k = threadIdx.x;
        if (k < K) {
            const float Nk = red[k];
            const float S  = red[K + k];
            float* pi_new      = out_tail;
            float* mu_new      = out_tail + K;
            float* log_cov_new = out_tail + K + K * P;

            pi_new[k] = Nk / (float)NPTS;
            const float invN = 1.f / Nk;
            float m2 = 0.f;
#pragma unroll
            for (int d = 0; d < P; ++d) {
                const float md = red[2 * K + d * K + k] * invN;
                mu_new[k * P + d] = md;
                m2 = fmaf(md, md, m2);
            }
            const float cov = (S - Nk * m2) / (32.f * Nk);
            log_cov_new[k] = logf(cov);
        }
    }
}

extern "C" void kernel_launch(void* const* d_in, const int* in_sizes, int n_in,
                              void* d_out, int out_size, void* d_ws, size_t ws_size,
                              hipStream_t stream)
{
    const float* mu_phi      = (const float*)d_in[0];
    const float* log_cov_phi = (const float*)d_in[1];
    const float* pi_k        = (const float*)d_in[2];
    const float* mu_k        = (const float*)d_in[3];
    const float* log_cov_k   = (const float*)d_in[4];
    float* out = (float*)d_out;
    float* ws  = (float*)d_ws;

    hipMemsetAsync(ws, 0, ((size_t)NCOPIES * WS_FLOATS + 1) * sizeof(float), stream);
    em_pass<<<NBLOCKS, NTHREADS, 0, stream>>>(mu_phi, log_cov_phi, pi_k, mu_k,
                                              log_cov_k, out,
                                              out + (size_t)NPTS * K, ws);
}